// Round 3
// baseline (2345.464 us; speedup 1.0000x reference)
//
#include <hip/hip_runtime.h>
#include <math.h>

// Problem dims (fixed): B=2, S=2048 -> TOK=4096 tokens; H=4096; I=11008
#define TOK 4096
#define HD  4096
#define ID  11008

typedef int i32x4 __attribute__((ext_vector_type(4)));

// ---------------------------------------------------------------- convert ---
__global__ void conv_i8(const float* __restrict__ in,
                        char* __restrict__ out, int n4) {
  int stride = gridDim.x * blockDim.x;
  for (int i = blockIdx.x * blockDim.x + threadIdx.x; i < n4; i += stride) {
    float4 v = ((const float4*)in)[i];
    char4 o;
    o.x = (char)(int)rintf(v.x);
    o.y = (char)(int)rintf(v.y);
    o.z = (char)(int)rintf(v.z);
    o.w = (char)(int)rintf(v.w);
    ((char4*)out)[i] = o;
  }
}

// ------------------------------------------------- fused gate+up GEMM -------
// Register-direct (no LDS, no barriers in K-loop). Each wave owns a 64x64
// output tile of BOTH gate and up. Fragment for mfma_i32_16x16x64_i8:
// lane reads 16B at row (lane&15), k-chunk (lane>>4)*16 -> one
// global_load_dwordx4 per fragment = 16 fully-consumed 64B lines.
// 1-deep software pipeline: next-stage loads issued before current MFMAs,
// so the compiler emits fine-grained vmcnt waits (AITER pattern), not a
// barrier drain. 2x2 waves/block share A rows / B cols -> L1 dedup.
__global__ __launch_bounds__(256, 2)
void gemm_gu(const char* __restrict__ A,
             const char* __restrict__ Bg,
             const char* __restrict__ Bu,
             float* __restrict__ gaOut,
             float* __restrict__ upOut,
             const float* __restrict__ xs,
             const float* __restrict__ wsg,
             double* __restrict__ sums)
{
  const int K = HD, N = ID;
  __shared__ double red[4];

  const int tid  = threadIdx.x;
  const int w    = tid >> 6;
  const int lane = tid & 63;
  const int wr   = lane & 15;
  const int qd   = lane >> 4;
  const int wm   = (w >> 1) << 6;
  const int wn   = (w & 1) << 6;

  // GROUP_M=8 swizzle (32 m-tiles = 4 groups)
  const int nbx = gridDim.x;
  const int L   = blockIdx.y * nbx + blockIdx.x;
  const int per = nbx << 3;
  const int grp = L / per;
  const int rem = L - grp * per;
  const int m0  = ((grp << 3) + (rem & 7)) << 7;
  const int n0  = (rem >> 3) << 7;

  const char* pa = A  + (size_t)(m0 + wm + wr) * K + (qd << 4);
  const char* pg = Bg + (size_t)(n0 + wn + wr) * K + (qd << 4);
  const char* pu = Bu + (size_t)(n0 + wn + wr) * K + (qd << 4);
  const size_t rstep = (size_t)16 * K;   // 16 rows

  i32x4 acg[4][4] = {};
  i32x4 acu[4][4] = {};
  i32x4 ca[4], cg[4], cu[4], na[4], ng[4], nu[4];

#pragma unroll
  for (int i = 0; i < 4; i++) {
    ca[i] = *(const i32x4*)(pa + i * rstep);
    cg[i] = *(const i32x4*)(pg + i * rstep);
    cu[i] = *(const i32x4*)(pu + i * rstep);
  }

  for (int k0 = 64; k0 < K; k0 += 64) {
#pragma unroll
    for (int i = 0; i < 4; i++) {
      na[i] = *(const i32x4*)(pa + k0 + i * rstep);
      ng[i] = *(const i32x4*)(pg + k0 + i * rstep);
      nu[i] = *(const i32x4*)(pu + k0 + i * rstep);
    }
#pragma unroll
    for (int i = 0; i < 4; i++)
#pragma unroll
      for (int j = 0; j < 4; j++) {
        acg[i][j] = __builtin_amdgcn_mfma_i32_16x16x64_i8(ca[i], cg[j],
                                                          acg[i][j], 0, 0, 0);
        acu[i][j] = __builtin_amdgcn_mfma_i32_16x16x64_i8(ca[i], cu[j],
                                                          acu[i][j], 0, 0, 0);
      }
#pragma unroll
    for (int i = 0; i < 4; i++) { ca[i] = na[i]; cg[i] = ng[i]; cu[i] = nu[i]; }
  }
#pragma unroll
  for (int i = 0; i < 4; i++)
#pragma unroll
    for (int j = 0; j < 4; j++) {
      acg[i][j] = __builtin_amdgcn_mfma_i32_16x16x64_i8(ca[i], cg[j],
                                                        acg[i][j], 0, 0, 0);
      acu[i][j] = __builtin_amdgcn_mfma_i32_16x16x64_i8(ca[i], cu[j],
                                                        acu[i][j], 0, 0, 0);
    }

  // epilogue: C/D layout col = lane&15 (n), row = quad*4 + reg (m)
  const float gs = xs[0] * wsg[0];
  double lsum = 0.0;
#pragma unroll
  for (int i = 0; i < 4; i++) {
    const int mb = m0 + wm + (i << 4) + (qd << 2);
#pragma unroll
    for (int j = 0; j < 4; j++) {
      const int n = n0 + wn + (j << 4) + wr;
#pragma unroll
      for (int r = 0; r < 4; r++) {
        float g = (float)acg[i][j][r] * gs;
        float s = g / (1.0f + expf(-g));              // silu
        gaOut[(size_t)(mb + r) * N + n] = s;
        upOut[(size_t)(mb + r) * N + n] = (float)acu[i][j][r];
        lsum += (double)fabsf(s);
      }
    }
  }

  for (int off = 32; off; off >>= 1) lsum += __shfl_down(lsum, off, 64);
  if (lane == 0) red[w] = lsum;
  __syncthreads();
  if (tid == 0) atomicAdd(&sums[0], red[0] + red[1] + red[2] + red[3]);
}

// ----------------------------------------------------- down GEMM ------------
__global__ __launch_bounds__(256, 3)
void gemm_dn(const char* __restrict__ A,
             const char* __restrict__ Bm,
             float* __restrict__ Cout)
{
  const int K = ID, N = HD;

  const int tid  = threadIdx.x;
  const int w    = tid >> 6;
  const int lane = tid & 63;
  const int wr   = lane & 15;
  const int qd   = lane >> 4;
  const int wm   = (w >> 1) << 6;
  const int wn   = (w & 1) << 6;

  const int nbx = gridDim.x;
  const int L   = blockIdx.y * nbx + blockIdx.x;
  const int per = nbx << 3;
  const int grp = L / per;
  const int rem = L - grp * per;
  const int m0  = ((grp << 3) + (rem & 7)) << 7;
  const int n0  = (rem >> 3) << 7;

  const char* pa = A  + (size_t)(m0 + wm + wr) * K + (qd << 4);
  const char* pb = Bm + (size_t)(n0 + wn + wr) * K + (qd << 4);
  const size_t rstep = (size_t)16 * K;

  i32x4 acc[4][4] = {};
  i32x4 ca[4], cb[4], na[4], nb[4];

#pragma unroll
  for (int i = 0; i < 4; i++) {
    ca[i] = *(const i32x4*)(pa + i * rstep);
    cb[i] = *(const i32x4*)(pb + i * rstep);
  }

  for (int k0 = 64; k0 < K; k0 += 64) {
#pragma unroll
    for (int i = 0; i < 4; i++) {
      na[i] = *(const i32x4*)(pa + k0 + i * rstep);
      nb[i] = *(const i32x4*)(pb + k0 + i * rstep);
    }
#pragma unroll
    for (int i = 0; i < 4; i++)
#pragma unroll
      for (int j = 0; j < 4; j++)
        acc[i][j] = __builtin_amdgcn_mfma_i32_16x16x64_i8(ca[i], cb[j],
                                                          acc[i][j], 0, 0, 0);
#pragma unroll
    for (int i = 0; i < 4; i++) { ca[i] = na[i]; cb[i] = nb[i]; }
  }
#pragma unroll
  for (int i = 0; i < 4; i++)
#pragma unroll
    for (int j = 0; j < 4; j++)
      acc[i][j] = __builtin_amdgcn_mfma_i32_16x16x64_i8(ca[i], cb[j],
                                                        acc[i][j], 0, 0, 0);

#pragma unroll
  for (int i = 0; i < 4; i++) {
    const int mb = m0 + wm + (i << 4) + (qd << 2);
#pragma unroll
    for (int j = 0; j < 4; j++) {
      const int n = n0 + wn + (j << 4) + wr;
#pragma unroll
      for (int r = 0; r < 4; r++)
        Cout[(size_t)(mb + r) * N + n] = (float)acc[i][j][r];
    }
  }
}

// ------------------------------------------------------- inter pass ---------
// inter = clip(rint(ga/ga_s)) * up * (ga_s*up_s); in-place over ga buffer.
// Numerics identical to R2's MODE1 epilogue.
__global__ void inter_pass(float* __restrict__ ga,          // in: ga, out: inter
                           const float* __restrict__ up,
                           const double* __restrict__ sums, long long NN,
                           const float* __restrict__ xs,
                           const float* __restrict__ wsu,
                           double* __restrict__ sums_out, int n4)
{
  __shared__ double red[4];
  const float up_s  = xs[0] * wsu[0];
  const float ga_s  = (float)(sums[0] / (double)NN) + 1e-8f;
  const float combo = ga_s * up_s;

  double lsum = 0.0;
  int stride = gridDim.x * blockDim.x;
  for (int i = blockIdx.x * blockDim.x + threadIdx.x; i < n4; i += stride) {
    float4 g = ((const float4*)ga)[i];
    float4 u = ((const float4*)up)[i];
    float4 o;
    o.x = fmaxf(-128.0f, fminf(127.0f, rintf(g.x / ga_s))) * u.x * combo;
    o.y = fmaxf(-128.0f, fminf(127.0f, rintf(g.y / ga_s))) * u.y * combo;
    o.z = fmaxf(-128.0f, fminf(127.0f, rintf(g.z / ga_s))) * u.z * combo;
    o.w = fmaxf(-128.0f, fminf(127.0f, rintf(g.w / ga_s))) * u.w * combo;
    ((float4*)ga)[i] = o;
    lsum += (double)fabsf(o.x) + (double)fabsf(o.y)
          + (double)fabsf(o.z) + (double)fabsf(o.w);
  }

  const int lane = threadIdx.x & 63, w = threadIdx.x >> 6;
  for (int off = 32; off; off >>= 1) lsum += __shfl_down(lsum, off, 64);
  if (lane == 0) red[w] = lsum;
  __syncthreads();
  if (threadIdx.x == 0)
    atomicAdd(&sums_out[0], red[0] + red[1] + red[2] + red[3]);
}

// ------------------------------------------------------------- quantize -----
__global__ void quant_inter(const float* __restrict__ inter,
                            char* __restrict__ outq,
                            const double* __restrict__ sums, long long NN,
                            const float* __restrict__ wsd,
                            float* __restrict__ scalar_out, int n4)
{
  const float is = (float)(sums[1] / (double)NN) + 1e-8f;
  if (blockIdx.x == 0 && threadIdx.x == 0) scalar_out[0] = is * wsd[0];
  int stride = gridDim.x * blockDim.x;
  for (int i = blockIdx.x * blockDim.x + threadIdx.x; i < n4; i += stride) {
    float4 v = ((const float4*)inter)[i];
    char4 o;
    o.x = (char)(int)fmaxf(-128.0f, fminf(127.0f, rintf(v.x / is)));
    o.y = (char)(int)fmaxf(-128.0f, fminf(127.0f, rintf(v.y / is)));
    o.z = (char)(int)fmaxf(-128.0f, fminf(127.0f, rintf(v.z / is)));
    o.w = (char)(int)fmaxf(-128.0f, fminf(127.0f, rintf(v.w / is)));
    ((char4*)outq)[i] = o;
  }
}

// ---------------------------------------------------------------- launch ----
extern "C" void kernel_launch(void* const* d_in, const int* in_sizes, int n_in,
                              void* d_out, int out_size, void* d_ws, size_t ws_size,
                              hipStream_t stream) {
  const float* x        = (const float*)d_in[0];
  const float* x_scale  = (const float*)d_in[1];
  const float* qw_gate  = (const float*)d_in[2];
  const float* ws_gate  = (const float*)d_in[3];
  const float* qw_up    = (const float*)d_in[4];
  const float* ws_up    = (const float*)d_in[5];
  const float* qw_down  = (const float*)d_in[6];
  const float* ws_down  = (const float*)d_in[7];
  float* out = (float*)d_out;

  char* ws = (char*)d_ws;
  double* sums = (double*)ws;                 // [0]=sum|ga| [1]=sum|inter|
  size_t off = 256;
  char* xq     = ws + off; off += (size_t)TOK * HD;
  char* wgq    = ws + off; off += (size_t)ID * HD;
  char* wuq    = ws + off; off += (size_t)ID * HD;
  char* wdq    = ws + off; off += (size_t)HD * ID;
  char* interq = ws + off; off += (size_t)TOK * ID;
  float* ga    = (float*)(ws + off); off += (size_t)TOK * ID * 4;  // becomes inter
  float* up    = (float*)(ws + off); off += (size_t)TOK * ID * 4;

  const long long NN = (long long)TOK * ID;

  hipMemsetAsync(sums, 0, 32, stream);

  conv_i8<<<4096, 256, 0, stream>>>(x,       xq,  TOK * HD / 4);
  conv_i8<<<8192, 256, 0, stream>>>(qw_gate, wgq, ID * HD / 4);
  conv_i8<<<8192, 256, 0, stream>>>(qw_up,   wuq, ID * HD / 4);
  conv_i8<<<8192, 256, 0, stream>>>(qw_down, wdq, HD * ID / 4);

  // fused gate+up GEMM: ga = silu(gate*gs), up raw; sum|ga| -> sums[0]
  gemm_gu<<<dim3(ID / 128, TOK / 128), 256, 0, stream>>>(
      xq, wgq, wuq, ga, up, x_scale, ws_gate, sums);

  // inter = clip(rint(ga/ga_s))*up*(ga_s*up_s), in-place; sum|inter| -> sums[1]
  inter_pass<<<8192, 256, 0, stream>>>(ga, up, sums, NN, x_scale, ws_up,
                                       sums + 1, (int)(NN / 4));

  // quantize inter -> int8; also write scalar output
  quant_inter<<<8192, 256, 0, stream>>>(ga, interq, sums, NN, ws_down,
                                        out + (size_t)TOK * HD, (int)(NN / 4));

  // down GEMM -> final output (exact integers in f32)
  gemm_dn<<<dim3(HD / 128, TOK / 128), 256, 0, stream>>>(interq, wdq, out);
}

// Round 4
// 1547.018 us; speedup vs baseline: 1.5161x; 1.5161x over previous
//
#include <hip/hip_runtime.h>
#include <math.h>

// Problem dims (fixed): B=2, S=2048 -> TOK=4096 tokens; H=4096; I=11008
#define TOK 4096
#define HD  4096
#define ID  11008

typedef int i32x4 __attribute__((ext_vector_type(4)));

#define GLDS16(g, l) __builtin_amdgcn_global_load_lds( \
    (const __attribute__((address_space(1))) void*)(g), \
    (__attribute__((address_space(3))) void*)(l), 16, 0, 0)

// ---------------------------------------------------------------- convert ---
// f32 -> int8. All values are exact small integers ({-1,0,1} weights,
// [-128,127] activations), so the cast is exact.
__global__ void conv_i8(const float* __restrict__ in,
                        char* __restrict__ out, int n4) {
  int stride = gridDim.x * blockDim.x;
  for (int i = blockIdx.x * blockDim.x + threadIdx.x; i < n4; i += stride) {
    float4 v = ((const float4*)in)[i];
    char4 o;
    o.x = (char)(int)rintf(v.x);
    o.y = (char)(int)rintf(v.y);
    o.z = (char)(int)rintf(v.z);
    o.w = (char)(int)rintf(v.w);
    ((char4*)out)[i] = o;
  }
}

// ----------------------------------------------------------------- GEMM -----
// out[m,n] = sum_k A[m,k]*B[n,k]  (both K-major int8), i32 accumulate (exact).
// m97 structure: 128x128 tile, 4 waves (2x2 of 64x64), 4x4 mfma_i32_16x16x64_i8
// per wave, K=64 per LDS stage, global_load_lds width=16.
//
// Staging (COALESCED, m97-style): thread t sources row t>>2, so lanes 0-3 read
// one aligned 64B span (16 cache lines per glds instr, not 64 like R2).
// LDS layout: row-major 64B rows with XOR swizzle — physical chunk p of row r
// holds logical chunk q = p ^ ((r>>1)&3). Fragment ds_read_b128 then hits 8
// distinct 4-bank groups per 16-lane phase (<=2-way = free). Both the staging
// chunk permutation and the fragment LDS offsets are loop-invariant.
//
// GROUP_M=8 block swizzle (kept from R2: cut FETCH 3.4x).
// MODE 0: gate -> ga = silu(acc*gs), store f32, sum|ga| -> sums[0]
// MODE 1: up   -> inter = clip(rint(ga/ga_s))*acc*(ga_s*up_s), store f32,
//                 sum|inter| -> sums[1]
// MODE 2: down -> plain f32 store (exact integers)
template<int MODE>
__global__ __launch_bounds__(256)
void gemm_i8(const char* __restrict__ A,
             const char* __restrict__ Bm,
             int M, int N, int K,
             float* __restrict__ Cout,
             const float* __restrict__ ga_in,
             const float* __restrict__ sc0,
             const float* __restrict__ sc1,
             double* __restrict__ sums,
             long long NN)
{
  __shared__ char As[8192];   // 128 rows x 64B, XOR-swizzled chunks
  __shared__ char Bs[8192];
  __shared__ double red[4];

  const int tid  = threadIdx.x;
  const int w    = tid >> 6;        // wave 0..3
  const int lane = tid & 63;
  const int wr   = lane & 15;
  const int qd   = lane >> 4;
  const int wm   = (w >> 1) << 6;
  const int wn   = (w & 1) << 6;

  // GROUP_M=8 swizzle (m-tile count is 32 for all three GEMMs: divisible)
  const int nbx = gridDim.x;
  const int L   = blockIdx.y * nbx + blockIdx.x;
  const int per = nbx << 3;
  const int grp = L / per;
  const int rem = L - grp * per;
  const int m0  = ((grp << 3) + (rem & 7)) << 7;
  const int n0  = (rem >> 3) << 7;

  i32x4 acc[4][4] = {};

  // staging: thread t -> row t>>2 (call 2: +64), logical chunk (t&3)^((t>>3)&3)
  const int rowL = tid >> 2;
  const int chk  = (tid & 3) ^ ((tid >> 3) & 3);
  const char* gA = A  + (size_t)(m0 + rowL) * K + (chk << 4);
  const char* gB = Bm + (size_t)(n0 + rowL) * K + (chk << 4);
  const size_t half = (size_t)64 * K;
  char* lA = As + (w << 10);        // wave-uniform dest: bytes [1024w, 1024w+1024)
  char* lB = Bs + (w << 10);

  // fragment LDS byte offsets (loop-invariant); frag i adds i*16 rows = i*1024B
  const int sw   = (wr >> 1) & 3;
  const int aoff = ((wm + wr) << 6) + ((qd ^ sw) << 4);
  const int boff = ((wn + wr) << 6) + ((qd ^ sw) << 4);

  for (int k0 = 0; k0 < K; k0 += 64) {
    GLDS16(gA + k0,        lA);
    GLDS16(gA + k0 + half, lA + 4096);
    GLDS16(gB + k0,        lB);
    GLDS16(gB + k0 + half, lB + 4096);
    __syncthreads();

    i32x4 af[4], bfr[4];
#pragma unroll
    for (int i = 0; i < 4; i++)
      af[i] = *(const i32x4*)(As + aoff + (i << 10));
#pragma unroll
    for (int j = 0; j < 4; j++)
      bfr[j] = *(const i32x4*)(Bs + boff + (j << 10));

#pragma unroll
    for (int i = 0; i < 4; i++)
#pragma unroll
      for (int j = 0; j < 4; j++)
        acc[i][j] = __builtin_amdgcn_mfma_i32_16x16x64_i8(af[i], bfr[j],
                                                          acc[i][j], 0, 0, 0);
    __syncthreads();
  }

  // epilogue: C/D layout col = lane&15 (n), row = quad*4 + reg (m)
  double lsum = 0.0;

  if (MODE == 0) {
    const float gs = sc0[0] * sc1[0];
#pragma unroll
    for (int i = 0; i < 4; i++) {
      const int mb = m0 + wm + (i << 4) + (qd << 2);
#pragma unroll
      for (int j = 0; j < 4; j++) {
        const int n = n0 + wn + (j << 4) + wr;
#pragma unroll
        for (int r = 0; r < 4; r++) {
          float g = (float)acc[i][j][r] * gs;
          float s = g / (1.0f + expf(-g));          // silu
          Cout[(size_t)(mb + r) * N + n] = s;
          lsum += (double)fabsf(s);
        }
      }
    }
  } else if (MODE == 1) {
    const float up_s  = sc0[0] * sc1[0];
    const float ga_s  = (float)(sums[0] / (double)NN) + 1e-8f;
    const float combo = ga_s * up_s;
#pragma unroll
    for (int i = 0; i < 4; i++) {
      const int mb = m0 + wm + (i << 4) + (qd << 2);
#pragma unroll
      for (int j = 0; j < 4; j++) {
        const int n = n0 + wn + (j << 4) + wr;
#pragma unroll
        for (int r = 0; r < 4; r++) {
          float up = (float)acc[i][j][r];
          float ga = ga_in[(size_t)(mb + r) * N + n];
          float gq = fmaxf(-128.0f, fminf(127.0f, rintf(ga / ga_s)));
          float itv = gq * up * combo;              // same assoc as reference
          Cout[(size_t)(mb + r) * N + n] = itv;
          lsum += (double)fabsf(itv);
        }
      }
    }
  } else {
#pragma unroll
    for (int i = 0; i < 4; i++) {
      const int mb = m0 + wm + (i << 4) + (qd << 2);
#pragma unroll
      for (int j = 0; j < 4; j++) {
        const int n = n0 + wn + (j << 4) + wr;
#pragma unroll
        for (int r = 0; r < 4; r++)
          Cout[(size_t)(mb + r) * N + n] = (float)acc[i][j][r];
      }
    }
  }

  if (MODE != 2) {
    for (int off = 32; off; off >>= 1) lsum += __shfl_down(lsum, off, 64);
    if (lane == 0) red[w] = lsum;
    __syncthreads();
    if (tid == 0) atomicAdd(&sums[MODE], red[0] + red[1] + red[2] + red[3]);
  }
}

// ------------------------------------------------------------- quantize -----
__global__ void quant_inter(const float* __restrict__ inter,
                            char* __restrict__ outq,
                            const double* __restrict__ sums, long long NN,
                            const float* __restrict__ wsd,
                            float* __restrict__ scalar_out, int n4)
{
  const float is = (float)(sums[1] / (double)NN) + 1e-8f;
  if (blockIdx.x == 0 && threadIdx.x == 0) scalar_out[0] = is * wsd[0];
  int stride = gridDim.x * blockDim.x;
  for (int i = blockIdx.x * blockDim.x + threadIdx.x; i < n4; i += stride) {
    float4 v = ((const float4*)inter)[i];
    char4 o;
    o.x = (char)(int)fmaxf(-128.0f, fminf(127.0f, rintf(v.x / is)));
    o.y = (char)(int)fmaxf(-128.0f, fminf(127.0f, rintf(v.y / is)));
    o.z = (char)(int)fmaxf(-128.0f, fminf(127.0f, rintf(v.z / is)));
    o.w = (char)(int)fmaxf(-128.0f, fminf(127.0f, rintf(v.w / is)));
    ((char4*)outq)[i] = o;
  }
}

// ---------------------------------------------------------------- launch ----
extern "C" void kernel_launch(void* const* d_in, const int* in_sizes, int n_in,
                              void* d_out, int out_size, void* d_ws, size_t ws_size,
                              hipStream_t stream) {
  const float* x        = (const float*)d_in[0];
  const float* x_scale  = (const float*)d_in[1];
  const float* qw_gate  = (const float*)d_in[2];
  const float* ws_gate  = (const float*)d_in[3];
  const float* qw_up    = (const float*)d_in[4];
  const float* ws_up    = (const float*)d_in[5];
  const float* qw_down  = (const float*)d_in[6];
  const float* ws_down  = (const float*)d_in[7];
  float* out = (float*)d_out;

  char* ws = (char*)d_ws;
  double* sums = (double*)ws;                 // [0]=sum|ga| [1]=sum|inter|
  size_t off = 256;
  char* xq     = ws + off; off += (size_t)TOK * HD;
  char* wgq    = ws + off; off += (size_t)ID * HD;
  char* wuq    = ws + off; off += (size_t)ID * HD;
  char* wdq    = ws + off; off += (size_t)HD * ID;
  char* interq = ws + off; off += (size_t)TOK * ID;
  float* ga    = (float*)(ws + off); off += (size_t)TOK * ID * 4;
  float* inter = (float*)(ws + off); off += (size_t)TOK * ID * 4;

  const long long NN = (long long)TOK * ID;

  hipMemsetAsync(sums, 0, 16, stream);

  conv_i8<<<4096, 256, 0, stream>>>(x,       xq,  TOK * HD / 4);
  conv_i8<<<8192, 256, 0, stream>>>(qw_gate, wgq, ID * HD / 4);
  conv_i8<<<8192, 256, 0, stream>>>(qw_up,   wuq, ID * HD / 4);
  conv_i8<<<8192, 256, 0, stream>>>(qw_down, wdq, HD * ID / 4);

  // gate GEMM + silu + sum|ga|
  gemm_i8<0><<<dim3(ID / 128, TOK / 128), 256, 0, stream>>>(
      xq, wgq, TOK, ID, HD, ga, nullptr, x_scale, ws_gate, sums, NN);

  // up GEMM + inter computation + sum|inter|
  gemm_i8<1><<<dim3(ID / 128, TOK / 128), 256, 0, stream>>>(
      xq, wuq, TOK, ID, HD, inter, ga, x_scale, ws_up, sums, NN);

  // quantize inter -> int8; also write scalar output
  quant_inter<<<8192, 256, 0, stream>>>(inter, interq, sums, NN, ws_down,
                                        out + (size_t)TOK * HD, (int)(NN / 4));

  // down GEMM -> final output (exact integers in f32)
  gemm_i8<2><<<dim3(HD / 128, TOK / 128), 256, 0, stream>>>(
      interq, wdq, TOK, HD, ID, out, nullptr, nullptr, nullptr, sums, NN);
}

// Round 5
// 1262.053 us; speedup vs baseline: 1.8585x; 1.2258x over previous
//
#include <hip/hip_runtime.h>
#include <math.h>

// Problem dims (fixed): B=2, S=2048 -> TOK=4096 tokens; H=4096; I=11008
#define TOK 4096
#define HD  4096
#define ID  11008

typedef int i32x4 __attribute__((ext_vector_type(4)));

#define GLDS16(g, l) __builtin_amdgcn_global_load_lds( \
    (const __attribute__((address_space(1))) void*)(g), \
    (__attribute__((address_space(3))) void*)(l), 16, 0, 0)

// ---------------------------------------------------------------- convert ---
__global__ void conv_i8(const float* __restrict__ in,
                        char* __restrict__ out, int n4) {
  int stride = gridDim.x * blockDim.x;
  for (int i = blockIdx.x * blockDim.x + threadIdx.x; i < n4; i += stride) {
    float4 v = ((const float4*)in)[i];
    char4 o;
    o.x = (char)(int)rintf(v.x);
    o.y = (char)(int)rintf(v.y);
    o.z = (char)(int)rintf(v.z);
    o.w = (char)(int)rintf(v.w);
    ((char4*)out)[i] = o;
  }
}

// ----------------------------------------------------------------- GEMM -----
// out[m,n] = sum_k A[m,k]*B[n,k]  (both K-major int8), i32 accumulate (exact).
// BK=128: 128x128 tile, K=128 per LDS stage -> 32 MFMA per barrier (2x R4),
// halving barrier-drain count. LDS 16KB/buffer, 32.8KB total.
//
// LDS layout: 128 rows x 8 chunks x 16B, physical chunk p = q ^ (row&7).
// Staging: 4 glds calls per buffer; call c covers rows 32c..32c+31; thread t
// -> row 32c + (t>>3), logical chunk (t&7)^((t>>3)&7). Dest = wave-uniform
// base + lane*16 (verified: rows 8w..8w+7 per wave per call). Lanes 0..7 read
// one aligned 128B span -> fully coalesced.
// Fragment read (k-half h, frag i): row r = wm+i*16+wr, p = (qd ^ (wr&7)),
// h toggles byte offset ^64. Per 16-lane phase: 8 chunk positions x2 = 2-way
// per bank group = free (m136).
//
// GROUP_M=8 block swizzle (R2: cut FETCH 3.4x).
// MODE 0: gate -> ga = silu(acc*gs), store f32, sum|ga| -> sums[0]
// MODE 1: up   -> inter = clip(rint(ga/ga_s))*acc*(ga_s*up_s), store f32,
//                 sum|inter| -> sums[1]
// MODE 2: down -> plain f32 store (exact integers)
template<int MODE>
__global__ __launch_bounds__(256, 3)
void gemm_i8(const char* __restrict__ A,
             const char* __restrict__ Bm,
             int M, int N, int K,
             float* __restrict__ Cout,
             const float* __restrict__ ga_in,
             const float* __restrict__ sc0,
             const float* __restrict__ sc1,
             double* __restrict__ sums,
             long long NN)
{
  __shared__ char As[16384];
  __shared__ char Bs[16384];
  __shared__ double red[4];

  const int tid  = threadIdx.x;
  const int w    = tid >> 6;        // wave 0..3
  const int lane = tid & 63;
  const int wr   = lane & 15;
  const int qd   = lane >> 4;
  const int wm   = (w >> 1) << 6;
  const int wn   = (w & 1) << 6;

  // GROUP_M=8 swizzle (m-tile count is 32 for all three GEMMs: divisible)
  const int nbx = gridDim.x;
  const int L   = blockIdx.y * nbx + blockIdx.x;
  const int per = nbx << 3;
  const int grp = L / per;
  const int rem = L - grp * per;
  const int m0  = ((grp << 3) + (rem & 7)) << 7;
  const int n0  = (rem >> 3) << 7;

  i32x4 acc[4][4] = {};

  // staging addresses
  const int rowL = tid >> 3;                    // 0..31
  const int chk  = (tid & 7) ^ (rowL & 7);
  const char* gA = A  + (size_t)(m0 + rowL) * K + (chk << 4);
  const char* gB = Bm + (size_t)(n0 + rowL) * K + (chk << 4);
  const size_t rk32 = (size_t)32 * K;
  char* lA = As + (w << 10);
  char* lB = Bs + (w << 10);

  // fragment LDS byte offsets (loop-invariant)
  const int s7    = wr & 7;
  const int abase = ((wm + wr) << 7) + ((qd ^ s7) << 4);
  const int bbase = ((wn + wr) << 7) + ((qd ^ s7) << 4);

  for (int k0 = 0; k0 < K; k0 += 128) {
    GLDS16(gA + k0,            lA);
    GLDS16(gA + k0 +     rk32, lA + 4096);
    GLDS16(gA + k0 + 2 * rk32, lA + 8192);
    GLDS16(gA + k0 + 3 * rk32, lA + 12288);
    GLDS16(gB + k0,            lB);
    GLDS16(gB + k0 +     rk32, lB + 4096);
    GLDS16(gB + k0 + 2 * rk32, lB + 8192);
    GLDS16(gB + k0 + 3 * rk32, lB + 12288);
    __syncthreads();

#pragma unroll
    for (int h = 0; h < 2; h++) {
      const int hx = h << 6;                    // toggles physical-chunk bit 2
      i32x4 af[4], bfr[4];
#pragma unroll
      for (int i = 0; i < 4; i++)
        af[i] = *(const i32x4*)(As + ((abase + (i << 11)) ^ hx));
#pragma unroll
      for (int j = 0; j < 4; j++)
        bfr[j] = *(const i32x4*)(Bs + ((bbase + (j << 11)) ^ hx));

#pragma unroll
      for (int i = 0; i < 4; i++)
#pragma unroll
        for (int j = 0; j < 4; j++)
          acc[i][j] = __builtin_amdgcn_mfma_i32_16x16x64_i8(af[i], bfr[j],
                                                            acc[i][j], 0, 0, 0);
    }
    __syncthreads();
  }

  // epilogue: C/D layout col = lane&15 (n), row = quad*4 + reg (m)
  double lsum = 0.0;

  if (MODE == 0) {
    const float gs = sc0[0] * sc1[0];
#pragma unroll
    for (int i = 0; i < 4; i++) {
      const int mb = m0 + wm + (i << 4) + (qd << 2);
#pragma unroll
      for (int j = 0; j < 4; j++) {
        const int n = n0 + wn + (j << 4) + wr;
#pragma unroll
        for (int r = 0; r < 4; r++) {
          float g = (float)acc[i][j][r] * gs;
          float s = g / (1.0f + expf(-g));          // silu
          Cout[(size_t)(mb + r) * N + n] = s;
          lsum += (double)fabsf(s);
        }
      }
    }
  } else if (MODE == 1) {
    const float up_s  = sc0[0] * sc1[0];
    const float ga_s  = (float)(sums[0] / (double)NN) + 1e-8f;
    const float combo = ga_s * up_s;
#pragma unroll
    for (int i = 0; i < 4; i++) {
      const int mb = m0 + wm + (i << 4) + (qd << 2);
#pragma unroll
      for (int j = 0; j < 4; j++) {
        const int n = n0 + wn + (j << 4) + wr;
#pragma unroll
        for (int r = 0; r < 4; r++) {
          float up = (float)acc[i][j][r];
          float ga = ga_in[(size_t)(mb + r) * N + n];
          float gq = fmaxf(-128.0f, fminf(127.0f, rintf(ga / ga_s)));
          float itv = gq * up * combo;              // same assoc as reference
          Cout[(size_t)(mb + r) * N + n] = itv;
          lsum += (double)fabsf(itv);
        }
      }
    }
  } else {
#pragma unroll
    for (int i = 0; i < 4; i++) {
      const int mb = m0 + wm + (i << 4) + (qd << 2);
#pragma unroll
      for (int j = 0; j < 4; j++) {
        const int n = n0 + wn + (j << 4) + wr;
#pragma unroll
        for (int r = 0; r < 4; r++)
          Cout[(size_t)(mb + r) * N + n] = (float)acc[i][j][r];
      }
    }
  }

  if (MODE != 2) {
    for (int off = 32; off; off >>= 1) lsum += __shfl_down(lsum, off, 64);
    if (lane == 0) red[w] = lsum;
    __syncthreads();
    if (tid == 0) atomicAdd(&sums[MODE], red[0] + red[1] + red[2] + red[3]);
  }
}

// ------------------------------------------------------------- quantize -----
__global__ void quant_inter(const float* __restrict__ inter,
                            char* __restrict__ outq,
                            const double* __restrict__ sums, long long NN,
                            const float* __restrict__ wsd,
                            float* __restrict__ scalar_out, int n4)
{
  const float is = (float)(sums[1] / (double)NN) + 1e-8f;
  if (blockIdx.x == 0 && threadIdx.x == 0) scalar_out[0] = is * wsd[0];
  int stride = gridDim.x * blockDim.x;
  for (int i = blockIdx.x * blockDim.x + threadIdx.x; i < n4; i += stride) {
    float4 v = ((const float4*)inter)[i];
    char4 o;
    o.x = (char)(int)fmaxf(-128.0f, fminf(127.0f, rintf(v.x / is)));
    o.y = (char)(int)fmaxf(-128.0f, fminf(127.0f, rintf(v.y / is)));
    o.z = (char)(int)fmaxf(-128.0f, fminf(127.0f, rintf(v.z / is)));
    o.w = (char)(int)fmaxf(-128.0f, fminf(127.0f, rintf(v.w / is)));
    ((char4*)outq)[i] = o;
  }
}

// ---------------------------------------------------------------- launch ----
extern "C" void kernel_launch(void* const* d_in, const int* in_sizes, int n_in,
                              void* d_out, int out_size, void* d_ws, size_t ws_size,
                              hipStream_t stream) {
  const float* x        = (const float*)d_in[0];
  const float* x_scale  = (const float*)d_in[1];
  const float* qw_gate  = (const float*)d_in[2];
  const float* ws_gate  = (const float*)d_in[3];
  const float* qw_up    = (const float*)d_in[4];
  const float* ws_up    = (const float*)d_in[5];
  const float* qw_down  = (const float*)d_in[6];
  const float* ws_down  = (const float*)d_in[7];
  float* out = (float*)d_out;

  char* ws = (char*)d_ws;
  double* sums = (double*)ws;                 // [0]=sum|ga| [1]=sum|inter|
  size_t off = 256;
  char* xq     = ws + off; off += (size_t)TOK * HD;
  char* wgq    = ws + off; off += (size_t)ID * HD;
  char* wuq    = ws + off; off += (size_t)ID * HD;
  char* wdq    = ws + off; off += (size_t)HD * ID;
  char* interq = ws + off; off += (size_t)TOK * ID;
  float* ga    = (float*)(ws + off); off += (size_t)TOK * ID * 4;
  float* inter = (float*)(ws + off); off += (size_t)TOK * ID * 4;

  const long long NN = (long long)TOK * ID;

  hipMemsetAsync(sums, 0, 16, stream);

  conv_i8<<<4096, 256, 0, stream>>>(x,       xq,  TOK * HD / 4);
  conv_i8<<<8192, 256, 0, stream>>>(qw_gate, wgq, ID * HD / 4);
  conv_i8<<<8192, 256, 0, stream>>>(qw_up,   wuq, ID * HD / 4);
  conv_i8<<<8192, 256, 0, stream>>>(qw_down, wdq, HD * ID / 4);

  // gate GEMM + silu + sum|ga|
  gemm_i8<0><<<dim3(ID / 128, TOK / 128), 256, 0, stream>>>(
      xq, wgq, TOK, ID, HD, ga, nullptr, x_scale, ws_gate, sums, NN);

  // up GEMM + inter computation + sum|inter|
  gemm_i8<1><<<dim3(ID / 128, TOK / 128), 256, 0, stream>>>(
      xq, wuq, TOK, ID, HD, inter, ga, x_scale, ws_up, sums, NN);

  // quantize inter -> int8; also write scalar output
  quant_inter<<<8192, 256, 0, stream>>>(inter, interq, sums, NN, ws_down,
                                        out + (size_t)TOK * HD, (int)(NN / 4));

  // down GEMM -> final output (exact integers in f32)
  gemm_i8<2><<<dim3(HD / 128, TOK / 128), 256, 0, stream>>>(
      interq, wdq, TOK, HD, ID, out, nullptr, nullptr, nullptr, sums, NN);
}

// Round 6
// 1165.917 us; speedup vs baseline: 2.0117x; 1.0825x over previous
//
#include <hip/hip_runtime.h>
#include <math.h>

// Problem dims (fixed): B=2, S=2048 -> TOK=4096 tokens; H=4096; I=11008
#define TOK 4096
#define HD  4096
#define ID  11008

typedef int i32x4 __attribute__((ext_vector_type(4)));

#define GLDS16(g, l) __builtin_amdgcn_global_load_lds( \
    (const __attribute__((address_space(1))) void*)(g), \
    (__attribute__((address_space(3))) void*)(l), 16, 0, 0)

// ---------------------------------------------------------------- convert ---
__global__ void conv_i8(const float* __restrict__ in,
                        char* __restrict__ out, int n4) {
  int stride = gridDim.x * blockDim.x;
  for (int i = blockIdx.x * blockDim.x + threadIdx.x; i < n4; i += stride) {
    float4 v = ((const float4*)in)[i];
    char4 o;
    o.x = (char)(int)rintf(v.x);
    o.y = (char)(int)rintf(v.y);
    o.z = (char)(int)rintf(v.z);
    o.w = (char)(int)rintf(v.w);
    ((char4*)out)[i] = o;
  }
}

// ----------------------------------------------------------------- GEMM -----
// out[m,n] = sum_k A[m,k]*B[n,k]  (both K-major int8), i32 accumulate (exact).
// BK=128: 128x128 tile, 32 MFMA per barrier. LDS 16KB/buffer (XOR-swizzled,
// conflict-free, verified R5: SQ_LDS_BANK_CONFLICT=0). Coalesced glds width=16.
//
// XCD-aware block swizzle (replaces R5's GROUP_M=8, which put the 8 blocks
// sharing a B-tile on 8 DIFFERENT XCDs -> 805MB FETCH): consecutive block IDs
// round-robin XCDs, so let x = L&7 track the XCD, r = L>>3:
//   n_tile = r>>2,  m_tile = x + (r&3)*8
// Per XCD: m-set {x,x+8,x+16,x+24} -> A working set 2MB, L2-resident; each
// B-tile used by 4 consecutive same-XCD blocks -> L2 hits; B (45MB) L3-hot.
// Requires exactly 32 m-tiles: true for all three GEMMs (TOK/128=32).
//
// MODE 0: gate -> ga = silu(acc*gs), store f32, sum|ga| -> sums[0]
// MODE 1: up   -> inter = clip(rint(ga/ga_s))*acc*(ga_s*up_s), store f32,
//                 sum|inter| -> sums[1]
// MODE 2: down -> plain f32 store (exact integers)
template<int MODE>
__global__ __launch_bounds__(256, 3)
void gemm_i8(const char* __restrict__ A,
             const char* __restrict__ Bm,
             int M, int N, int K,
             float* __restrict__ Cout,
             const float* __restrict__ ga_in,
             const float* __restrict__ sc0,
             const float* __restrict__ sc1,
             double* __restrict__ sums,
             long long NN)
{
  __shared__ char As[16384];
  __shared__ char Bs[16384];
  __shared__ double red[4];

  const int tid  = threadIdx.x;
  const int w    = tid >> 6;        // wave 0..3
  const int lane = tid & 63;
  const int wr   = lane & 15;
  const int qd   = lane >> 4;
  const int wm   = (w >> 1) << 6;
  const int wn   = (w & 1) << 6;

  // XCD-aware swizzle (bijection over all (m_tile, n_tile))
  const int L   = blockIdx.y * gridDim.x + blockIdx.x;
  const int xcd = L & 7;
  const int r   = L >> 3;
  const int m0  = (xcd + ((r & 3) << 3)) << 7;
  const int n0  = (r >> 2) << 7;

  i32x4 acc[4][4] = {};

  // staging addresses
  const int rowL = tid >> 3;                    // 0..31
  const int chk  = (tid & 7) ^ (rowL & 7);
  const char* gA = A  + (size_t)(m0 + rowL) * K + (chk << 4);
  const char* gB = Bm + (size_t)(n0 + rowL) * K + (chk << 4);
  const size_t rk32 = (size_t)32 * K;
  char* lA = As + (w << 10);
  char* lB = Bs + (w << 10);

  // fragment LDS byte offsets (loop-invariant)
  const int s7    = wr & 7;
  const int abase = ((wm + wr) << 7) + ((qd ^ s7) << 4);
  const int bbase = ((wn + wr) << 7) + ((qd ^ s7) << 4);

  for (int k0 = 0; k0 < K; k0 += 128) {
    GLDS16(gA + k0,            lA);
    GLDS16(gA + k0 +     rk32, lA + 4096);
    GLDS16(gA + k0 + 2 * rk32, lA + 8192);
    GLDS16(gA + k0 + 3 * rk32, lA + 12288);
    GLDS16(gB + k0,            lB);
    GLDS16(gB + k0 +     rk32, lB + 4096);
    GLDS16(gB + k0 + 2 * rk32, lB + 8192);
    GLDS16(gB + k0 + 3 * rk32, lB + 12288);
    __syncthreads();

#pragma unroll
    for (int h = 0; h < 2; h++) {
      const int hx = h << 6;                    // toggles physical-chunk bit 2
      i32x4 af[4], bfr[4];
#pragma unroll
      for (int i = 0; i < 4; i++)
        af[i] = *(const i32x4*)(As + ((abase + (i << 11)) ^ hx));
#pragma unroll
      for (int j = 0; j < 4; j++)
        bfr[j] = *(const i32x4*)(Bs + ((bbase + (j << 11)) ^ hx));

#pragma unroll
      for (int i = 0; i < 4; i++)
#pragma unroll
        for (int j = 0; j < 4; j++)
          acc[i][j] = __builtin_amdgcn_mfma_i32_16x16x64_i8(af[i], bfr[j],
                                                            acc[i][j], 0, 0, 0);
    }
    __syncthreads();
  }

  // epilogue: C/D layout col = lane&15 (n), row = quad*4 + reg (m)
  double lsum = 0.0;

  if (MODE == 0) {
    const float gs = sc0[0] * sc1[0];
#pragma unroll
    for (int i = 0; i < 4; i++) {
      const int mb = m0 + wm + (i << 4) + (qd << 2);
#pragma unroll
      for (int j = 0; j < 4; j++) {
        const int n = n0 + wn + (j << 4) + wr;
#pragma unroll
        for (int r2 = 0; r2 < 4; r2++) {
          float g = (float)acc[i][j][r2] * gs;
          float s = g / (1.0f + expf(-g));          // silu
          Cout[(size_t)(mb + r2) * N + n] = s;
          lsum += (double)fabsf(s);
        }
      }
    }
  } else if (MODE == 1) {
    const float up_s  = sc0[0] * sc1[0];
    const float ga_s  = (float)(sums[0] / (double)NN) + 1e-8f;
    const float combo = ga_s * up_s;
#pragma unroll
    for (int i = 0; i < 4; i++) {
      const int mb = m0 + wm + (i << 4) + (qd << 2);
#pragma unroll
      for (int j = 0; j < 4; j++) {
        const int n = n0 + wn + (j << 4) + wr;
#pragma unroll
        for (int r2 = 0; r2 < 4; r2++) {
          float up = (float)acc[i][j][r2];
          float ga = ga_in[(size_t)(mb + r2) * N + n];
          float gq = fmaxf(-128.0f, fminf(127.0f, rintf(ga / ga_s)));
          float itv = gq * up * combo;              // same assoc as reference
          Cout[(size_t)(mb + r2) * N + n] = itv;
          lsum += (double)fabsf(itv);
        }
      }
    }
  } else {
#pragma unroll
    for (int i = 0; i < 4; i++) {
      const int mb = m0 + wm + (i << 4) + (qd << 2);
#pragma unroll
      for (int j = 0; j < 4; j++) {
        const int n = n0 + wn + (j << 4) + wr;
#pragma unroll
        for (int r2 = 0; r2 < 4; r2++)
          Cout[(size_t)(mb + r2) * N + n] = (float)acc[i][j][r2];
      }
    }
  }

  if (MODE != 2) {
    for (int off = 32; off; off >>= 1) lsum += __shfl_down(lsum, off, 64);
    if (lane == 0) red[w] = lsum;
    __syncthreads();
    if (tid == 0) atomicAdd(&sums[MODE], red[0] + red[1] + red[2] + red[3]);
  }
}

// ------------------------------------------------------------- quantize -----
__global__ void quant_inter(const float* __restrict__ inter,
                            char* __restrict__ outq,
                            const double* __restrict__ sums, long long NN,
                            const float* __restrict__ wsd,
                            float* __restrict__ scalar_out, int n4)
{
  const float is = (float)(sums[1] / (double)NN) + 1e-8f;
  if (blockIdx.x == 0 && threadIdx.x == 0) scalar_out[0] = is * wsd[0];
  int stride = gridDim.x * blockDim.x;
  for (int i = blockIdx.x * blockDim.x + threadIdx.x; i < n4; i += stride) {
    float4 v = ((const float4*)inter)[i];
    char4 o;
    o.x = (char)(int)fmaxf(-128.0f, fminf(127.0f, rintf(v.x / is)));
    o.y = (char)(int)fmaxf(-128.0f, fminf(127.0f, rintf(v.y / is)));
    o.z = (char)(int)fmaxf(-128.0f, fminf(127.0f, rintf(v.z / is)));
    o.w = (char)(int)fmaxf(-128.0f, fminf(127.0f, rintf(v.w / is)));
    ((char4*)outq)[i] = o;
  }
}

// ---------------------------------------------------------------- launch ----
extern "C" void kernel_launch(void* const* d_in, const int* in_sizes, int n_in,
                              void* d_out, int out_size, void* d_ws, size_t ws_size,
                              hipStream_t stream) {
  const float* x        = (const float*)d_in[0];
  const float* x_scale  = (const float*)d_in[1];
  const float* qw_gate  = (const float*)d_in[2];
  const float* ws_gate  = (const float*)d_in[3];
  const float* qw_up    = (const float*)d_in[4];
  const float* ws_up    = (const float*)d_in[5];
  const float* qw_down  = (const float*)d_in[6];
  const float* ws_down  = (const float*)d_in[7];
  float* out = (float*)d_out;

  char* ws = (char*)d_ws;
  double* sums = (double*)ws;                 // [0]=sum|ga| [1]=sum|inter|
  size_t off = 256;
  char* xq     = ws + off; off += (size_t)TOK * HD;
  char* wgq    = ws + off; off += (size_t)ID * HD;
  char* wuq    = ws + off; off += (size_t)ID * HD;
  char* wdq    = ws + off; off += (size_t)HD * ID;
  char* interq = ws + off; off += (size_t)TOK * ID;
  float* ga    = (float*)(ws + off); off += (size_t)TOK * ID * 4;
  float* inter = (float*)(ws + off); off += (size_t)TOK * ID * 4;

  const long long NN = (long long)TOK * ID;

  hipMemsetAsync(sums, 0, 16, stream);

  conv_i8<<<4096, 256, 0, stream>>>(x,       xq,  TOK * HD / 4);
  conv_i8<<<8192, 256, 0, stream>>>(qw_gate, wgq, ID * HD / 4);
  conv_i8<<<8192, 256, 0, stream>>>(qw_up,   wuq, ID * HD / 4);
  conv_i8<<<8192, 256, 0, stream>>>(qw_down, wdq, HD * ID / 4);

  // gate GEMM + silu + sum|ga|
  gemm_i8<0><<<dim3(ID / 128, TOK / 128), 256, 0, stream>>>(
      xq, wgq, TOK, ID, HD, ga, nullptr, x_scale, ws_gate, sums, NN);

  // up GEMM + inter computation + sum|inter|
  gemm_i8<1><<<dim3(ID / 128, TOK / 128), 256, 0, stream>>>(
      xq, wuq, TOK, ID, HD, inter, ga, x_scale, ws_up, sums, NN);

  // quantize inter -> int8; also write scalar output
  quant_inter<<<8192, 256, 0, stream>>>(inter, interq, sums, NN, ws_down,
                                        out + (size_t)TOK * HD, (int)(NN / 4));

  // down GEMM -> final output (exact integers in f32)
  gemm_i8<2><<<dim3(HD / 128, TOK / 128), 256, 0, stream>>>(
      interq, wdq, TOK, HD, ID, out, nullptr, nullptr, nullptr, sums, NN);
}

// Round 8
// 1124.211 us; speedup vs baseline: 2.0863x; 1.0371x over previous
//
#include <hip/hip_runtime.h>
#include <math.h>

// Problem dims (fixed): B=2, S=2048 -> TOK=4096 tokens; H=4096; I=11008
#define TOK 4096
#define HD  4096
#define ID  11008

typedef int i32x4 __attribute__((ext_vector_type(4)));
typedef float f32x4v __attribute__((ext_vector_type(4)));  // ext-vector: OK for nontemporal builtins
typedef char i8x4v __attribute__((ext_vector_type(4)));

#define GLDS16(g, l) __builtin_amdgcn_global_load_lds( \
    (const __attribute__((address_space(1))) void*)(g), \
    (__attribute__((address_space(3))) void*)(l), 16, 0, 0)

// ---------------------------------------------------------------- convert ---
// All four f32 -> i8 converts fused into one launch. Reads are streamed-once
// (765MB) -> non-temporal so they don't thrash L3 ahead of the GEMMs; writes
// (191MB i8 total) stay cacheable -> L3-resident for the GEMMs that read them.
__global__ void conv_all(const float* __restrict__ x,  char* __restrict__ xq,
                         const float* __restrict__ wg, char* __restrict__ wgq,
                         const float* __restrict__ wu, char* __restrict__ wuq,
                         const float* __restrict__ wd, char* __restrict__ wdq)
{
  const long NX = (long)TOK * HD / 4, NW = (long)ID * HD / 4;
  const long total = NX + 3 * NW;
  const long stride = (long)gridDim.x * blockDim.x;
  for (long i = (long)blockIdx.x * blockDim.x + threadIdx.x; i < total;
       i += stride) {
    const f32x4v* src; i8x4v* dst; long j;
    if (i < NX)               { src = (const f32x4v*)x;  dst = (i8x4v*)xq;  j = i; }
    else if (i < NX + NW)     { src = (const f32x4v*)wg; dst = (i8x4v*)wgq; j = i - NX; }
    else if (i < NX + 2 * NW) { src = (const f32x4v*)wu; dst = (i8x4v*)wuq; j = i - NX - NW; }
    else                      { src = (const f32x4v*)wd; dst = (i8x4v*)wdq; j = i - NX - 2 * NW; }
    f32x4v v = __builtin_nontemporal_load(&src[j]);
    i8x4v o;
    o.x = (char)(int)rintf(v.x);
    o.y = (char)(int)rintf(v.y);
    o.z = (char)(int)rintf(v.z);
    o.w = (char)(int)rintf(v.w);
    dst[j] = o;
  }
}

// ----------------------------------------------------------------- GEMM -----
// out[m,n] = sum_k A[m,k]*B[n,k]  (both K-major int8), i32 accumulate (exact).
// BK=128, 128x128 tile, 32 MFMA per barrier, XOR-swizzled LDS (0 conflicts),
// coalesced glds width=16, XCD-aware block swizzle (R6: FETCH 805->328MB).
// R7: all epilogue stores NON-TEMPORAL + MODE1 ga_in loads non-temporal, so
// streaming f32 traffic stops evicting B from L2/L3 (B re-fetch was ~7x ->
// every stage's vmcnt(0) barrier-drain paid HBM-miss latency ~950cyc).
//
// MODE 0: gate -> ga = silu(acc*gs), store f32, sum|ga| -> sums[0]
// MODE 1: up   -> inter = clip(rint(ga/ga_s))*acc*(ga_s*up_s), store f32,
//                 sum|inter| -> sums[1]
// MODE 2: down -> plain f32 store (exact integers)
template<int MODE>
__global__ __launch_bounds__(256, 3)
void gemm_i8(const char* __restrict__ A,
             const char* __restrict__ Bm,
             int M, int N, int K,
             float* __restrict__ Cout,
             const float* __restrict__ ga_in,
             const float* __restrict__ sc0,
             const float* __restrict__ sc1,
             double* __restrict__ sums,
             long long NN)
{
  __shared__ char As[16384];
  __shared__ char Bs[16384];
  __shared__ double red[4];

  const int tid  = threadIdx.x;
  const int w    = tid >> 6;        // wave 0..3
  const int lane = tid & 63;
  const int wr   = lane & 15;
  const int qd   = lane >> 4;
  const int wm   = (w >> 1) << 6;
  const int wn   = (w & 1) << 6;

  // XCD-aware swizzle (bijection over all (m_tile, n_tile))
  const int L   = blockIdx.y * gridDim.x + blockIdx.x;
  const int xcd = L & 7;
  const int r   = L >> 3;
  const int m0  = (xcd + ((r & 3) << 3)) << 7;
  const int n0  = (r >> 2) << 7;

  i32x4 acc[4][4] = {};

  // staging addresses
  const int rowL = tid >> 3;                    // 0..31
  const int chk  = (tid & 7) ^ (rowL & 7);
  const char* gA = A  + (size_t)(m0 + rowL) * K + (chk << 4);
  const char* gB = Bm + (size_t)(n0 + rowL) * K + (chk << 4);
  const size_t rk32 = (size_t)32 * K;
  char* lA = As + (w << 10);
  char* lB = Bs + (w << 10);

  // fragment LDS byte offsets (loop-invariant)
  const int s7    = wr & 7;
  const int abase = ((wm + wr) << 7) + ((qd ^ s7) << 4);
  const int bbase = ((wn + wr) << 7) + ((qd ^ s7) << 4);

  for (int k0 = 0; k0 < K; k0 += 128) {
    GLDS16(gA + k0,            lA);
    GLDS16(gA + k0 +     rk32, lA + 4096);
    GLDS16(gA + k0 + 2 * rk32, lA + 8192);
    GLDS16(gA + k0 + 3 * rk32, lA + 12288);
    GLDS16(gB + k0,            lB);
    GLDS16(gB + k0 +     rk32, lB + 4096);
    GLDS16(gB + k0 + 2 * rk32, lB + 8192);
    GLDS16(gB + k0 + 3 * rk32, lB + 12288);
    __syncthreads();

#pragma unroll
    for (int h = 0; h < 2; h++) {
      const int hx = h << 6;                    // toggles physical-chunk bit 2
      i32x4 af[4], bfr[4];
#pragma unroll
      for (int i = 0; i < 4; i++)
        af[i] = *(const i32x4*)(As + ((abase + (i << 11)) ^ hx));
#pragma unroll
      for (int j = 0; j < 4; j++)
        bfr[j] = *(const i32x4*)(Bs + ((bbase + (j << 11)) ^ hx));

#pragma unroll
      for (int i = 0; i < 4; i++)
#pragma unroll
        for (int j = 0; j < 4; j++)
          acc[i][j] = __builtin_amdgcn_mfma_i32_16x16x64_i8(af[i], bfr[j],
                                                            acc[i][j], 0, 0, 0);
    }
    __syncthreads();
  }

  // epilogue: C/D layout col = lane&15 (n), row = quad*4 + reg (m)
  double lsum = 0.0;

  if (MODE == 0) {
    const float gs = sc0[0] * sc1[0];
#pragma unroll
    for (int i = 0; i < 4; i++) {
      const int mb = m0 + wm + (i << 4) + (qd << 2);
#pragma unroll
      for (int j = 0; j < 4; j++) {
        const int n = n0 + wn + (j << 4) + wr;
#pragma unroll
        for (int r2 = 0; r2 < 4; r2++) {
          float g = (float)acc[i][j][r2] * gs;
          float s = g / (1.0f + expf(-g));          // silu
          __builtin_nontemporal_store(s, &Cout[(size_t)(mb + r2) * N + n]);
          lsum += (double)fabsf(s);
        }
      }
    }
  } else if (MODE == 1) {
    const float up_s  = sc0[0] * sc1[0];
    const float ga_s  = (float)(sums[0] / (double)NN) + 1e-8f;
    const float combo = ga_s * up_s;
#pragma unroll
    for (int i = 0; i < 4; i++) {
      const int mb = m0 + wm + (i << 4) + (qd << 2);
#pragma unroll
      for (int j = 0; j < 4; j++) {
        const int n = n0 + wn + (j << 4) + wr;
#pragma unroll
        for (int r2 = 0; r2 < 4; r2++) {
          float up = (float)acc[i][j][r2];
          float ga = __builtin_nontemporal_load(
                         &ga_in[(size_t)(mb + r2) * N + n]);
          float gq = fmaxf(-128.0f, fminf(127.0f, rintf(ga / ga_s)));
          float itv = gq * up * combo;              // same assoc as reference
          __builtin_nontemporal_store(itv, &Cout[(size_t)(mb + r2) * N + n]);
          lsum += (double)fabsf(itv);
        }
      }
    }
  } else {
#pragma unroll
    for (int i = 0; i < 4; i++) {
      const int mb = m0 + wm + (i << 4) + (qd << 2);
#pragma unroll
      for (int j = 0; j < 4; j++) {
        const int n = n0 + wn + (j << 4) + wr;
#pragma unroll
        for (int r2 = 0; r2 < 4; r2++)
          __builtin_nontemporal_store((float)acc[i][j][r2],
                                      &Cout[(size_t)(mb + r2) * N + n]);
      }
    }
  }

  if (MODE != 2) {
    for (int off = 32; off; off >>= 1) lsum += __shfl_down(lsum, off, 64);
    if (lane == 0) red[w] = lsum;
    __syncthreads();
    if (tid == 0) atomicAdd(&sums[MODE], red[0] + red[1] + red[2] + red[3]);
  }
}

// ------------------------------------------------------------- quantize -----
__global__ void quant_inter(const float* __restrict__ inter,
                            char* __restrict__ outq,
                            const double* __restrict__ sums, long long NN,
                            const float* __restrict__ wsd,
                            float* __restrict__ scalar_out, int n4)
{
  const float is = (float)(sums[1] / (double)NN) + 1e-8f;
  if (blockIdx.x == 0 && threadIdx.x == 0) scalar_out[0] = is * wsd[0];
  int stride = gridDim.x * blockDim.x;
  for (int i = blockIdx.x * blockDim.x + threadIdx.x; i < n4; i += stride) {
    f32x4v v = __builtin_nontemporal_load(&((const f32x4v*)inter)[i]);
    i8x4v o;
    o.x = (char)(int)fmaxf(-128.0f, fminf(127.0f, rintf(v.x / is)));
    o.y = (char)(int)fmaxf(-128.0f, fminf(127.0f, rintf(v.y / is)));
    o.z = (char)(int)fmaxf(-128.0f, fminf(127.0f, rintf(v.z / is)));
    o.w = (char)(int)fmaxf(-128.0f, fminf(127.0f, rintf(v.w / is)));
    ((i8x4v*)outq)[i] = o;                 // cacheable: GEMM2 reads it next
  }
}

// ---------------------------------------------------------------- launch ----
extern "C" void kernel_launch(void* const* d_in, const int* in_sizes, int n_in,
                              void* d_out, int out_size, void* d_ws, size_t ws_size,
                              hipStream_t stream) {
  const float* x        = (const float*)d_in[0];
  const float* x_scale  = (const float*)d_in[1];
  const float* qw_gate  = (const float*)d_in[2];
  const float* ws_gate  = (const float*)d_in[3];
  const float* qw_up    = (const float*)d_in[4];
  const float* ws_up    = (const float*)d_in[5];
  const float* qw_down  = (const float*)d_in[6];
  const float* ws_down  = (const float*)d_in[7];
  float* out = (float*)d_out;

  char* ws = (char*)d_ws;
  double* sums = (double*)ws;                 // [0]=sum|ga| [1]=sum|inter|
  size_t off = 256;
  char* xq     = ws + off; off += (size_t)TOK * HD;
  char* wgq    = ws + off; off += (size_t)ID * HD;
  char* wuq    = ws + off; off += (size_t)ID * HD;
  char* wdq    = ws + off; off += (size_t)HD * ID;
  char* interq = ws + off; off += (size_t)TOK * ID;
  float* ga    = (float*)(ws + off); off += (size_t)TOK * ID * 4;
  float* inter = (float*)(ws + off); off += (size_t)TOK * ID * 4;

  const long long NN = (long long)TOK * ID;

  (void)hipMemsetAsync(sums, 0, 16, stream);

  // all four converts in one launch
  conv_all<<<8192, 256, 0, stream>>>(x, xq, qw_gate, wgq, qw_up, wuq,
                                     qw_down, wdq);

  // gate GEMM + silu + sum|ga|
  gemm_i8<0><<<dim3(ID / 128, TOK / 128), 256, 0, stream>>>(
      xq, wgq, TOK, ID, HD, ga, nullptr, x_scale, ws_gate, sums, NN);

  // up GEMM + inter computation + sum|inter|
  gemm_i8<1><<<dim3(ID / 128, TOK / 128), 256, 0, stream>>>(
      xq, wuq, TOK, ID, HD, inter, ga, x_scale, ws_up, sums, NN);

  // quantize inter -> int8; also write scalar output
  quant_inter<<<8192, 256, 0, stream>>>(inter, interq, sums, NN, ws_down,
                                        out + (size_t)TOK * HD, (int)(NN / 4));

  // down GEMM -> final output (exact integers in f32)
  gemm_i8<2><<<dim3(HD / 128, TOK / 128), 256, 0, stream>>>(
      interq, wdq, TOK, HD, ID, out, nullptr, nullptr, nullptr, sums, NN);
}